// Round 1
// 1386.173 us; speedup vs baseline: 1.1469x; 1.1469x over previous
//
#include <hip/hip_runtime.h>
#include <cstdint>
#include <cstddef>

#define T_TOK 4096
#define H_DIM 2048
#define I_DIM 4096
#define E_NUM 8
#define CAP_ROWS 9216   // max padded rows: 8192 + 8*127 = 9208, rounded up

// ---------------- workspace layout (bytes) ----------------
#define OFF_COUNTS   0                               // int[8]
#define OFF_CURSOR   64                              // int[8]
#define OFF_PADOFF   128                             // int[9]
#define OFF_TOKIDX   1024                            // int[CAP_ROWS]
#define OFF_TOKGATE  (OFF_TOKIDX + CAP_ROWS*4)       // float[CAP_ROWS]
#define OFF_XQ       ((size_t)(OFF_TOKGATE + CAP_ROWS*4))     // fp8[CAP][H]
#define XQ_BYTES     ((size_t)CAP_ROWS*H_DIM)
#define OFF_AQ       (OFF_XQ + XQ_BYTES)                       // fp8[CAP][I]
#define AQ_BYTES     ((size_t)CAP_ROWS*I_DIM)
#define OFF_W1B      (OFF_AQ + AQ_BYTES)                       // fp8[E][2I][H]
#define W1B_BYTES    ((size_t)E_NUM*2*I_DIM*H_DIM)
#define OFF_W2B      (OFF_W1B + W1B_BYTES)                     // fp8[E][H][I]

typedef float f32x4 __attribute__((ext_vector_type(4)));

// RNE round of f32 to the fp8 e4m3fn grid (after clip to +-448), returned as f32.
__device__ __forceinline__ float fp8_round(float v) {
  v = fminf(448.f, fmaxf(-448.f, v));
  float av = fabsf(v);
  if (av < 0.015625f) {                 // below min normal 2^-6: subnormal grid, step 2^-9
    return rintf(v * 512.f) * (1.f / 512.f);
  }
  unsigned u = __float_as_uint(v);
  unsigned lsb = (u >> 20) & 1u;        // RNE to 3 mantissa bits
  u += 0x7FFFFu + lsb;
  u &= 0xFFF00000u;
  return __uint_as_float(u);
}

// Exact e4m3fn encode of a value ALREADY on the fp8 grid (|q| <= 448).
// Bit-manipulation only -> no dependence on HW cvt rounding semantics.
__device__ __forceinline__ unsigned fp8_enc(float q) {
  unsigned u = __float_as_uint(q);
  unsigned s = (u >> 24) & 0x80u;
  float aq = fabsf(q);
  if (aq < 0.015625f) {                 // subnormal: value = m * 2^-9, m in 0..7
    return s | (unsigned)(int)rintf(aq * 512.f);
  }
  unsigned e = (u >> 23) & 0xFFu;       // 121..135
  unsigned man = (u >> 20) & 7u;
  return s | ((e - 120u) << 3) | man;
}

__device__ __forceinline__ void gld16(const void* g, void* l) {
  __builtin_amdgcn_global_load_lds(
      (__attribute__((address_space(1))) void*)((void*)g),
      (__attribute__((address_space(3))) void*)l, 16, 0, 0);
}

// ---------------- routing ----------------
__global__ void k_count(const int* __restrict__ se, int* __restrict__ counts) {
  int t = blockIdx.x * 256 + threadIdx.x;
  if (t >= T_TOK) return;
  int e0 = se[t * 2], e1 = se[t * 2 + 1];
  atomicAdd(&counts[e0], 1);
  if (e1 != e0) atomicAdd(&counts[e1], 1);
}

__global__ void k_offsets(const int* __restrict__ counts, int* __restrict__ padOff) {
  if (threadIdx.x == 0 && blockIdx.x == 0) {
    int acc = 0;
    for (int e = 0; e < E_NUM; e++) {
      padOff[e] = acc;
      acc += ((counts[e] + 127) / 128) * 128;
    }
    padOff[E_NUM] = acc;
  }
}

__global__ void k_fill(const int* __restrict__ se, const float* __restrict__ rw,
                       const int* __restrict__ padOff, int* __restrict__ cursor,
                       int* __restrict__ tokIdx, float* __restrict__ tokGate) {
  int t = blockIdx.x * 256 + threadIdx.x;
  if (t >= T_TOK) return;
  int e0 = se[t * 2], e1 = se[t * 2 + 1];
  float w0 = rw[t * 2], w1 = rw[t * 2 + 1];
  float g0 = w0 + (e1 == e0 ? w1 : 0.f);
  int s0 = atomicAdd(&cursor[e0], 1);
  tokIdx[padOff[e0] + s0] = t;
  tokGate[padOff[e0] + s0] = g0;
  if (e1 != e0) {
    int s1 = atomicAdd(&cursor[e1], 1);
    tokIdx[padOff[e1] + s1] = t;
    tokGate[padOff[e1] + s1] = w1;
  }
}

// ---------------- gather + quantize x -> fp8 ----------------
__global__ __launch_bounds__(256)
void k_gather(const float* __restrict__ x, const int* __restrict__ padOff,
              const int* __restrict__ counts, const int* __restrict__ tokIdx,
              const float* __restrict__ w1_is, unsigned char* __restrict__ xq) {
  const int rblk = blockIdx.x;
  const int total = padOff[E_NUM];
  if (rblk >= total) return;
  int e = 0;
  while (rblk >= padOff[e + 1]) e++;
  unsigned char* dst = xq + (size_t)rblk * H_DIM;
  const int c = threadIdx.x * 8;
  const int local = rblk - padOff[e];
  if (local >= counts[e]) {           // pad row -> zeros
    *(uint2*)(dst + c) = make_uint2(0u, 0u);
    return;
  }
  const int tok = tokIdx[rblk];
  const float is = w1_is[e];
  const float* src = x + (size_t)tok * H_DIM + c;
  float4 v0 = *(const float4*)(src);
  float4 v1 = *(const float4*)(src + 4);
  unsigned lo = fp8_enc(fp8_round(v0.x / is))
              | (fp8_enc(fp8_round(v0.y / is)) << 8)
              | (fp8_enc(fp8_round(v0.z / is)) << 16)
              | (fp8_enc(fp8_round(v0.w / is)) << 24);
  unsigned hi = fp8_enc(fp8_round(v1.x / is))
              | (fp8_enc(fp8_round(v1.y / is)) << 8)
              | (fp8_enc(fp8_round(v1.z / is)) << 16)
              | (fp8_enc(fp8_round(v1.w / is)) << 24);
  *(uint2*)(dst + c) = make_uint2(lo, hi);
}

// ---------------- weight convert f32 -> fp8 (exact; inputs are on the grid) ----------------
__global__ __launch_bounds__(256)
void k_wconv(const float* __restrict__ w, unsigned char* __restrict__ o, long n8) {
  long i = (long)blockIdx.x * 256 + threadIdx.x;
  if (i >= n8) return;
  const float4* src = (const float4*)w + i * 2;
  float4 v0 = src[0];
  float4 v1 = src[1];
  unsigned lo = fp8_enc(v0.x) | (fp8_enc(v0.y) << 8) | (fp8_enc(v0.z) << 16) | (fp8_enc(v0.w) << 24);
  unsigned hi = fp8_enc(v1.x) | (fp8_enc(v1.y) << 8) | (fp8_enc(v1.z) << 16) | (fp8_enc(v1.w) << 24);
  ((uint2*)o)[i] = make_uint2(lo, hi);
}

// ---------------- GEMM1: h = xq @ w1^T (fp8 MFMA), fused silu*u + requant ----------------
// grid: (I/128, 32, E); block 512 (8 waves, wave tile 64x32, dual g/u accum), BK=64
// LDS tiles [128][64] fp8, linear for global_load_lds; bank-conflict-free via
// both-sides 16B-chunk XOR swizzle: chunk ^= (row>>2)&3 (pre-swizzled global src + swizzled ds_read).
__global__ __launch_bounds__(512, 1)
void k_gemm1(const unsigned char* __restrict__ xq,
             const unsigned char* __restrict__ w1b,
             const int* __restrict__ padOff,
             const float* __restrict__ w1_is, const float* __restrict__ w1_ws,
             const float* __restrict__ w2_is,
             unsigned char* __restrict__ aq) {
  const int e = blockIdx.z;
  const int rbase = padOff[e];
  const int rows = padOff[e + 1] - rbase;
  const int mt = blockIdx.y;
  if (mt * 128 >= rows) return;
  const int nt = blockIdx.x;

  __shared__ __align__(16) unsigned char As[128 * 64];
  __shared__ __align__(16) unsigned char Bg[128 * 64];
  __shared__ __align__(16) unsigned char Bu[128 * 64];

  const int tid = threadIdx.x;
  const int lane = tid & 63;
  const int wave = tid >> 6;
  const int wm = wave >> 2, wn = wave & 3;
  const int lr = lane & 15, quad = lane >> 4;
  const int qh = quad >> 1, ql = quad & 1;
  const int swz = (lr >> 2) & 3;
  // ds_read byte offsets within a row, for MFMA k-subtile 0 / 1 (global chunk = ksub*2+qh, XORed)
  const int cs0 = (((0 + qh) ^ swz) << 4) + ql * 8;
  const int cs1 = (((2 + qh) ^ swz) << 4) + ql * 8;

  const int r = tid >> 2;
  const int kb = tid & 3;
  const int kbs = (kb ^ ((r >> 2) & 3)) * 16;   // pre-swizzled source chunk
  const unsigned char* pa = xq + (size_t)(rbase + mt * 128 + r) * H_DIM + kbs;
  const unsigned char* pg = w1b + ((size_t)e * 2 * I_DIM + nt * 128 + r) * H_DIM + kbs;
  const unsigned char* pu = pg + (size_t)I_DIM * H_DIM;
  unsigned char* la = As + tid * 16;
  unsigned char* lg = Bg + tid * 16;
  unsigned char* lu = Bu + tid * 16;

  f32x4 accg[4][2] = {};
  f32x4 accu[4][2] = {};

  for (int k0 = 0; k0 < H_DIM; k0 += 64) {
    gld16(pa + k0, la);
    gld16(pg + k0, lg);
    gld16(pu + k0, lu);
    __syncthreads();
    long af[4][2], gf[2][2], uf[2][2];
#pragma unroll
    for (int i = 0; i < 4; i++) {
      const unsigned char* ba = As + (wm * 64 + i * 16 + lr) * 64;
      af[i][0] = *(const long*)(ba + cs0);
      af[i][1] = *(const long*)(ba + cs1);
    }
#pragma unroll
    for (int j = 0; j < 2; j++) {
      const unsigned char* bg = Bg + (wn * 32 + j * 16 + lr) * 64;
      const unsigned char* bu = Bu + (wn * 32 + j * 16 + lr) * 64;
      gf[j][0] = *(const long*)(bg + cs0);
      gf[j][1] = *(const long*)(bg + cs1);
      uf[j][0] = *(const long*)(bu + cs0);
      uf[j][1] = *(const long*)(bu + cs1);
    }
#pragma unroll
    for (int i = 0; i < 4; i++)
#pragma unroll
      for (int j = 0; j < 2; j++) {
        accg[i][j] = __builtin_amdgcn_mfma_f32_16x16x32_fp8_fp8(af[i][0], gf[j][0], accg[i][j], 0, 0, 0);
        accg[i][j] = __builtin_amdgcn_mfma_f32_16x16x32_fp8_fp8(af[i][1], gf[j][1], accg[i][j], 0, 0, 0);
        accu[i][j] = __builtin_amdgcn_mfma_f32_16x16x32_fp8_fp8(af[i][0], uf[j][0], accu[i][j], 0, 0, 0);
        accu[i][j] = __builtin_amdgcn_mfma_f32_16x16x32_fp8_fp8(af[i][1], uf[j][1], accu[i][j], 0, 0, 0);
      }
    __syncthreads();
  }

  const float s1 = w1_is[e] * w1_ws[e];
  const float is2 = w2_is[e];
#pragma unroll
  for (int i = 0; i < 4; i++)
#pragma unroll
    for (int j = 0; j < 2; j++)
#pragma unroll
      for (int rr = 0; rr < 4; rr++) {
        const int row = wm * 64 + i * 16 + quad * 4 + rr;
        const int col = nt * 128 + wn * 32 + j * 16 + lr;
        float g = accg[i][j][rr] * s1;
        float u = accu[i][j][rr] * s1;
        float a = (g / (1.f + expf(-g))) * u;   // silu(g)*u
        float q = fp8_round(a / is2);
        aq[(size_t)(rbase + mt * 128 + row) * I_DIM + col] = (unsigned char)fp8_enc(q);
      }
}

// ---------------- GEMM2: y = aq @ w2^T (fp8 MFMA), scale*gate, scatter-add ----------------
// grid: (H/128, 32, E); block 512, BK=64
__global__ __launch_bounds__(512, 1)
void k_gemm2(const unsigned char* __restrict__ aq,
             const unsigned char* __restrict__ w2b,
             const int* __restrict__ padOff, const int* __restrict__ counts,
             const int* __restrict__ tokIdx, const float* __restrict__ tokGate,
             const float* __restrict__ w2_is, const float* __restrict__ w2_ws,
             float* __restrict__ out) {
  const int e = blockIdx.z;
  const int rbase = padOff[e];
  const int rows = padOff[e + 1] - rbase;
  const int mt = blockIdx.y;
  if (mt * 128 >= rows) return;
  const int nt = blockIdx.x;
  const int cnt = counts[e];

  __shared__ __align__(16) unsigned char As[128 * 64];
  __shared__ __align__(16) unsigned char Bs[128 * 64];
  __shared__ int sTok[128];
  __shared__ float sGate[128];

  const int tid = threadIdx.x;
  const int lane = tid & 63;
  const int wave = tid >> 6;
  const int wm = wave >> 2, wn = wave & 3;
  const int lr = lane & 15, quad = lane >> 4;
  const int qh = quad >> 1, ql = quad & 1;
  const int swz = (lr >> 2) & 3;
  const int cs0 = (((0 + qh) ^ swz) << 4) + ql * 8;
  const int cs1 = (((2 + qh) ^ swz) << 4) + ql * 8;

  if (tid < 128) {
    int rr = mt * 128 + tid;
    if (rr < cnt) { sTok[tid] = tokIdx[rbase + rr]; sGate[tid] = tokGate[rbase + rr]; }
    else          { sTok[tid] = -1;                 sGate[tid] = 0.f; }
  }

  const int r = tid >> 2;
  const int kb = tid & 3;
  const int kbs = (kb ^ ((r >> 2) & 3)) * 16;
  const unsigned char* pa = aq + (size_t)(rbase + mt * 128 + r) * I_DIM + kbs;
  const unsigned char* pb = w2b + ((size_t)e * H_DIM + nt * 128 + r) * I_DIM + kbs;
  unsigned char* la = As + tid * 16;
  unsigned char* lb = Bs + tid * 16;

  f32x4 acc[4][2] = {};

  for (int k0 = 0; k0 < I_DIM; k0 += 64) {
    gld16(pa + k0, la);
    gld16(pb + k0, lb);
    __syncthreads();
    long af[4][2], bf[2][2];
#pragma unroll
    for (int i = 0; i < 4; i++) {
      const unsigned char* ba = As + (wm * 64 + i * 16 + lr) * 64;
      af[i][0] = *(const long*)(ba + cs0);
      af[i][1] = *(const long*)(ba + cs1);
    }
#pragma unroll
    for (int j = 0; j < 2; j++) {
      const unsigned char* bb = Bs + (wn * 32 + j * 16 + lr) * 64;
      bf[j][0] = *(const long*)(bb + cs0);
      bf[j][1] = *(const long*)(bb + cs1);
    }
#pragma unroll
    for (int i = 0; i < 4; i++)
#pragma unroll
      for (int j = 0; j < 2; j++) {
        acc[i][j] = __builtin_amdgcn_mfma_f32_16x16x32_fp8_fp8(af[i][0], bf[j][0], acc[i][j], 0, 0, 0);
        acc[i][j] = __builtin_amdgcn_mfma_f32_16x16x32_fp8_fp8(af[i][1], bf[j][1], acc[i][j], 0, 0, 0);
      }
    __syncthreads();
  }

  const float s2 = w2_is[e] * w2_ws[e];
#pragma unroll
  for (int i = 0; i < 4; i++)
#pragma unroll
    for (int j = 0; j < 2; j++)
#pragma unroll
      for (int rr = 0; rr < 4; rr++) {
        const int row = wm * 64 + i * 16 + quad * 4 + rr;
        const int tk = sTok[row];
        if (tk >= 0) {
          const int col = nt * 128 + wn * 32 + j * 16 + lr;
          unsafeAtomicAdd(out + (size_t)tk * H_DIM + col, sGate[row] * s2 * acc[i][j][rr]);
        }
      }
}

// ---------------- host launch ----------------
extern "C" void kernel_launch(void* const* d_in, const int* in_sizes, int n_in,
                              void* d_out, int out_size, void* d_ws, size_t ws_size,
                              hipStream_t stream) {
  const float* x     = (const float*)d_in[0];
  const int*   se    = (const int*)d_in[1];
  const float* rw    = (const float*)d_in[2];
  const float* w1    = (const float*)d_in[3];
  const float* w2    = (const float*)d_in[4];
  const float* w1_is = (const float*)d_in[5];
  const float* w2_is = (const float*)d_in[6];
  const float* w1_ws = (const float*)d_in[7];
  const float* w2_ws = (const float*)d_in[8];
  float* out = (float*)d_out;
  char* ws = (char*)d_ws;

  int*   counts  = (int*)(ws + OFF_COUNTS);
  int*   cursor  = (int*)(ws + OFF_CURSOR);
  int*   padOff  = (int*)(ws + OFF_PADOFF);
  int*   tokIdx  = (int*)(ws + OFF_TOKIDX);
  float* tokGate = (float*)(ws + OFF_TOKGATE);
  unsigned char* xq  = (unsigned char*)(ws + OFF_XQ);
  unsigned char* aq  = (unsigned char*)(ws + OFF_AQ);
  unsigned char* w1b = (unsigned char*)(ws + OFF_W1B);
  unsigned char* w2b = (unsigned char*)(ws + OFF_W2B);

  hipMemsetAsync(ws, 0, 1024, stream);
  hipMemsetAsync(d_out, 0, (size_t)T_TOK * H_DIM * sizeof(float), stream);

  k_count  <<<16, 256, 0, stream>>>(se, counts);
  k_offsets<<<1, 1, 0, stream>>>(counts, padOff);
  k_fill   <<<16, 256, 0, stream>>>(se, rw, padOff, cursor, tokIdx, tokGate);
  k_gather <<<CAP_ROWS, 256, 0, stream>>>(x, padOff, counts, tokIdx, w1_is, xq);

  k_wconv<<<65536, 256, 0, stream>>>(w1, w1b, (long)E_NUM * 2 * I_DIM * H_DIM / 8);
  k_wconv<<<32768, 256, 0, stream>>>(w2, w2b, (long)E_NUM * H_DIM * I_DIM / 8);

  dim3 g1(I_DIM / 128, 32, E_NUM);
  k_gemm1<<<g1, 512, 0, stream>>>(xq, w1b, padOff, w1_is, w1_ws, w2_is, aq);

  dim3 g2(H_DIM / 128, 32, E_NUM);
  k_gemm2<<<g2, 512, 0, stream>>>(aq, w2b, padOff, counts, tokIdx, tokGate, w2_is, w2_ws, out);
}